// Round 13
// baseline (148.031 us; speedup 1.0000x reference)
//
#include <hip/hip_runtime.h>

// FBSNN loss — single fused kernel, bf16 MFMA 16x16x32, zero-shuffle layout.
//
// Round 13 = round 12 structure + issue-count surgery (the producer wave is
// ISSUE-bound: ~70% of its SIMD's issue slots busy — r10/r12 counters):
//   * v_cvt_pk_bf16_f32 (gfx950 packed f32->bf16 RNE) replaces the 5-op
//     manual pack, guarded by __has_builtin with manual fallback.
//   * biases held as f32x4 and fed DIRECTLY as MFMA C operands (no per-tile
//     element-wise copies).
//   * hoisted zero f32x4 for tangent/output accumulator inits.
//
// 256 blocks x 192 threads (3 waves, 1 block/CU, paths 16*blk..16*blk+15):
//   wave 0  = producer: sequential q-net scan, writes y_n, q_n to LDS,
//             one __syncthreads per step.
//   waves 1,2 = consumers: Y-net + forward tangent, software-pipelined over
//             two barrier intervals: half A (input + h0) in interval n+1,
//             half B (h1+h2+out) in interval n+2, alternating parity.
//   epilogue: residuals from LDS + dW, one atomicAdd per block.
// Barrier audit: producer 50+1+2 = 53, consumers 53 intervals, one epilogue
// barrier. Per interval exactly one of {halfA(j), halfB(j-1)} fires per
// consumer (consecutive parities), so pipeline state is never clobbered.
//
// Unit relabeling u = 8*qd + 4t + i (t<2; +32 for t>=2): each lane's 4 C/D
// tiles ARE its two next-layer B-frags in register order (zero cross-lane).
// Weights/biases prescaled by 1/2pi; tangent dh = cosrev(cf) * (2pi * Ct).

#define NPATH   4096
#define NSTEP   50
#define DT_F    0.02f
#define SQRT_DT 0.14142136f
#define SIGMA_F 0.5f
#define INV2PI  0.15915494309189535f
#define TWOPI_F 6.28318530717958648f

typedef __attribute__((ext_vector_type(8)))  short s16x8;
typedef __attribute__((ext_vector_type(4)))  float f32x4;

#if __has_builtin(__builtin_amdgcn_cvt_pk_bf16_f32)
__device__ __forceinline__ unsigned pkbf(float a, float b) {
    auto r = __builtin_amdgcn_cvt_pk_bf16_f32(a, b);   // RNE, 1 instr
    unsigned u; __builtin_memcpy(&u, &r, 4); return u;
}
#else
__device__ __forceinline__ unsigned pkbf(float a, float b) {
    unsigned ua = __float_as_uint(a), ub = __float_as_uint(b);
    ua += 0x7fffu + ((ua >> 16) & 1u);
    ub += 0x7fffu + ((ub >> 16) & 1u);
    return (ua >> 16) | (ub & 0xffff0000u);
}
#endif

__device__ __forceinline__ s16x8 frag4(unsigned a, unsigned b, unsigned c, unsigned d) {
    union { unsigned u[4]; s16x8 s; } x;
    x.u[0] = a; x.u[1] = b; x.u[2] = c; x.u[3] = d;
    return x.s;
}

__device__ __forceinline__ float sinrev(float x) {
#if __has_builtin(__builtin_amdgcn_sinf)
    return __builtin_amdgcn_sinf(x);
#else
    return __sinf(x * TWOPI_F);
#endif
}
__device__ __forceinline__ float cosrev(float x) {
#if __has_builtin(__builtin_amdgcn_cosf)
    return __builtin_amdgcn_cosf(x);
#else
    return __cosf(x * TWOPI_F);
#endif
}

// output unit produced at (tile t, C/D-row r)
__device__ __forceinline__ int slot16(int t, int r) {
    return (t < 2) ? 8 * (r >> 2) + 4 * t + (r & 3)
                   : 32 + 8 * (r >> 2) + 4 * (t - 2) + (r & 3);
}

struct NetFrags {
    s16x8 Ain[4];
    s16x8 AH[3][4][2];
    s16x8 Aout[2];
    f32x4 bIn[4];          // C-init vectors, consumed directly by MFMA
    f32x4 bHd[3][4];
    float bout;
};

__device__ __forceinline__ void build_net(
    const float* __restrict__ Win, const float* __restrict__ bin,
    const float* __restrict__ Whid, const float* __restrict__ bhid,
    const float* __restrict__ Wout, const float* __restrict__ bo,
    int qd, int m, NetFrags& NF)
{
#pragma unroll
    for (int t = 0; t < 4; ++t) {
        const int uo = slot16(t, m);
        unsigned w0 = 0;
        if (qd == 0) w0 = pkbf(INV2PI * Win[uo], INV2PI * Win[64 + uo]);
        NF.Ain[t] = frag4(w0, 0u, 0u, 0u);
#pragma unroll
        for (int L = 0; L < 3; ++L) {
            const float* W = Whid + L * 4096 + uo;
#pragma unroll
            for (int kk = 0; kk < 2; ++kk) {
                unsigned w[4];
#pragma unroll
                for (int j2 = 0; j2 < 4; ++j2) {
                    int e0 = 32 * kk + 8 * qd + 2 * j2;
                    w[j2] = pkbf(INV2PI * W[e0 * 64], INV2PI * W[(e0 + 1) * 64]);
                }
                NF.AH[L][t][kk] = frag4(w[0], w[1], w[2], w[3]);
            }
        }
#pragma unroll
        for (int i = 0; i < 4; ++i) {
            const int u = slot16(t, 4 * qd + i);
            NF.bIn[t][i] = INV2PI * bin[u];
#pragma unroll
            for (int L = 0; L < 3; ++L)
                NF.bHd[L][t][i] = INV2PI * bhid[L * 64 + u];
        }
    }
#pragma unroll
    for (int kk = 0; kk < 2; ++kk) {
        unsigned w[4] = {0u, 0u, 0u, 0u};
        if (m == 0) {
#pragma unroll
            for (int j2 = 0; j2 < 4; ++j2) {
                int e0 = 32 * kk + 8 * qd + 2 * j2;
                w[j2] = pkbf(Wout[e0], Wout[e0 + 1]);
            }
        }
        NF.Aout[kk] = frag4(w[0], w[1], w[2], w[3]);
    }
    NF.bout = bo[0];
}

// fwd transition: 4 C tiles -> 2 B-frags (sin + packed cvt)
__device__ __forceinline__ void trans16(const f32x4* C, s16x8& B0, s16x8& B1) {
    float a[4][4];
#pragma unroll
    for (int t = 0; t < 4; ++t)
#pragma unroll
        for (int i = 0; i < 4; ++i) a[t][i] = sinrev(C[t][i]);
    B0 = frag4(pkbf(a[0][0], a[0][1]), pkbf(a[0][2], a[0][3]),
               pkbf(a[1][0], a[1][1]), pkbf(a[1][2], a[1][3]));
    B1 = frag4(pkbf(a[2][0], a[2][1]), pkbf(a[2][2], a[2][3]),
               pkbf(a[3][0], a[3][1]), pkbf(a[3][2], a[3][3]));
}

// fwd+tangent transition
__device__ __forceinline__ void trans16t(const f32x4* Cf, const f32x4* Ct,
                                         s16x8& Bf0, s16x8& Bf1,
                                         s16x8& Bt0, s16x8& Bt1)
{
    float s[4][4], d[4][4];
#pragma unroll
    for (int t = 0; t < 4; ++t)
#pragma unroll
        for (int i = 0; i < 4; ++i) {
            float cf = Cf[t][i];
            s[t][i] = sinrev(cf);
            d[t][i] = cosrev(cf) * (TWOPI_F * Ct[t][i]);
        }
    Bf0 = frag4(pkbf(s[0][0], s[0][1]), pkbf(s[0][2], s[0][3]),
                pkbf(s[1][0], s[1][1]), pkbf(s[1][2], s[1][3]));
    Bf1 = frag4(pkbf(s[2][0], s[2][1]), pkbf(s[2][2], s[2][3]),
                pkbf(s[3][0], s[3][1]), pkbf(s[3][2], s[3][3]));
    Bt0 = frag4(pkbf(d[0][0], d[0][1]), pkbf(d[0][2], d[0][3]),
                pkbf(d[1][0], d[1][1]), pkbf(d[1][2], d[1][3]));
    Bt1 = frag4(pkbf(d[2][0], d[2][1]), pkbf(d[2][2], d[2][3]),
                pkbf(d[3][0], d[3][1]), pkbf(d[3][2], d[3][3]));
}

// one hidden layer with tangent: bias vec as C operand, zero vec for tangent
__device__ __forceinline__ void hidden_tan(const NetFrags& NF, int L,
    const f32x4& zc,
    const s16x8& Bf0, const s16x8& Bf1, const s16x8& Bt0, const s16x8& Bt1,
    f32x4* Cf, f32x4* Ct)
{
#pragma unroll
    for (int t = 0; t < 4; ++t) {
        f32x4 c = __builtin_amdgcn_mfma_f32_16x16x32_bf16(NF.AH[L][t][0], Bf0, NF.bHd[L][t], 0, 0, 0);
        Cf[t]   = __builtin_amdgcn_mfma_f32_16x16x32_bf16(NF.AH[L][t][1], Bf1, c, 0, 0, 0);
        f32x4 z = __builtin_amdgcn_mfma_f32_16x16x32_bf16(NF.AH[L][t][0], Bt0, zc, 0, 0, 0);
        Ct[t]   = __builtin_amdgcn_mfma_f32_16x16x32_bf16(NF.AH[L][t][1], Bt1, z, 0, 0, 0);
    }
}

// ================= fused kernel =================

extern "C" __global__ void __launch_bounds__(192, 1)
fbsnn_fused(const float* __restrict__ Y_Win, const float* __restrict__ Y_bin,
            const float* __restrict__ Y_Whid, const float* __restrict__ Y_bhid,
            const float* __restrict__ Y_Wout, const float* __restrict__ Y_bout,
            const float* __restrict__ q_Win, const float* __restrict__ q_bin,
            const float* __restrict__ q_Whid, const float* __restrict__ q_bhid,
            const float* __restrict__ q_Wout, const float* __restrict__ q_bout,
            const float* __restrict__ y0p, const float* __restrict__ dW,
            float* __restrict__ out)
{
    __shared__ float yb[51 * 16];      // y trajectory
    __shared__ float qb[50 * 16];      // control
    __shared__ float Yb[51 * 16];      // Y-net value
    __shared__ float dYb[51 * 16];     // Y-net tangent
    __shared__ float partial[3];

    const int tid = (int)threadIdx.x;
    const int wv  = tid >> 6;          // 0 = producer, 1/2 = consumers
    const int l   = tid & 63;
    const int qd  = l >> 4;
    const int m   = l & 15;
    const int p   = (int)blockIdx.x * 16 + m;

    const f32x4 zc = {0.0f, 0.0f, 0.0f, 0.0f};

    if (wv == 0) {
        // ---------------- producer: q-net scan ----------------
        NetFrags NF;
        build_net(q_Win, q_bin, q_Whid, q_bhid, q_Wout, q_bout, qd, m, NF);

        float y = y0p[0];
        float dw_cur = (qd == 0) ? dW[p] : 0.0f;

        for (int n = 0; n < NSTEP; ++n) {
            const float tt = n * DT_F;
            if (qd == 0) yb[n * 16 + m] = y;

            const int n1 = (n + 1 < NSTEP) ? n + 1 : NSTEP - 1;
            const float dw_next = (qd == 0) ? dW[n1 * NPATH + p] : 0.0f;

            const s16x8 Bty = frag4((qd == 0) ? pkbf(tt, y) : 0u, 0u, 0u, 0u);

            f32x4 C[4];
#pragma unroll
            for (int t = 0; t < 4; ++t)
                C[t] = __builtin_amdgcn_mfma_f32_16x16x32_bf16(NF.Ain[t], Bty, NF.bIn[t], 0, 0, 0);
            s16x8 B0, B1;
            trans16(C, B0, B1);

#pragma unroll
            for (int L = 0; L < 3; ++L) {
#pragma unroll
                for (int t = 0; t < 4; ++t) {
                    f32x4 c = __builtin_amdgcn_mfma_f32_16x16x32_bf16(NF.AH[L][t][0], B0, NF.bHd[L][t], 0, 0, 0);
                    C[t]    = __builtin_amdgcn_mfma_f32_16x16x32_bf16(NF.AH[L][t][1], B1, c, 0, 0, 0);
                }
                trans16(C, B0, B1);
            }

            f32x4 Co = __builtin_amdgcn_mfma_f32_16x16x32_bf16(NF.Aout[0], B0, zc, 0, 0, 0);
            Co = __builtin_amdgcn_mfma_f32_16x16x32_bf16(NF.Aout[1], B1, Co, 0, 0, 0);

            const float q = Co[0] + NF.bout;         // valid at qd==0, col=m
            if (qd == 0) qb[n * 16 + m] = q;
            y = fmaf(q, DT_F, y) + SIGMA_F * (dw_cur * SQRT_DT);
            dw_cur = dw_next;

            __syncthreads();                         // barriers 1..50
        }
        if (qd == 0) yb[NSTEP * 16 + m] = y;
        __syncthreads();                             // barrier 51
        __syncthreads();                             // barrier 52 (consumer tail)
        __syncthreads();                             // barrier 53 (consumer tail)
    } else {
        // -------- consumers: Y-net + tangent, 2-interval pipeline --------
        NetFrags NF;
        build_net(Y_Win, Y_bin, Y_Whid, Y_bhid, Y_Wout, Y_bout, qd, m, NF);

        const int parity = wv - 1;
        const s16x8 Btn = frag4((qd == 0) ? pkbf(0.0f, 1.0f) : 0u, 0u, 0u, 0u);

        s16x8 Bf0, Bf1, Bt0, Bt1;                    // pipeline state (post-h0)

        for (int j = 0; j < 53; ++j) {
            __syncthreads();                         // barriers 1..53
            const int kB = j - 1;                    // step finishing this interval
            const int kA = j;                        // step starting this interval
            // exactly one of the two fires (consecutive parities)
            if (kB >= 0 && kB <= NSTEP && (kB & 1) == parity) {
                // ---- half B: h1, h2, output, store ----
                f32x4 Cf[4], Ct[4];
                hidden_tan(NF, 1, zc, Bf0, Bf1, Bt0, Bt1, Cf, Ct);
                s16x8 bf0, bf1, bt0, bt1;
                trans16t(Cf, Ct, bf0, bf1, bt0, bt1);
                hidden_tan(NF, 2, zc, bf0, bf1, bt0, bt1, Cf, Ct);
                trans16t(Cf, Ct, bf0, bf1, bt0, bt1);

                f32x4 Cof = __builtin_amdgcn_mfma_f32_16x16x32_bf16(NF.Aout[0], bf0, zc, 0, 0, 0);
                Cof = __builtin_amdgcn_mfma_f32_16x16x32_bf16(NF.Aout[1], bf1, Cof, 0, 0, 0);
                f32x4 Cot = __builtin_amdgcn_mfma_f32_16x16x32_bf16(NF.Aout[0], bt0, zc, 0, 0, 0);
                Cot = __builtin_amdgcn_mfma_f32_16x16x32_bf16(NF.Aout[1], bt1, Cot, 0, 0, 0);

                if (qd == 0) {
                    Yb[kB * 16 + m]  = Cof[0] + NF.bout;
                    dYb[kB * 16 + m] = Cot[0];
                }
            }
            if (kA <= NSTEP && (kA & 1) == parity) {
                // ---- half A: input layer + h0 -> pipeline state ----
                const float yv = yb[kA * 16 + m];
                const float tt = kA * DT_F;
                const s16x8 Bty = frag4((qd == 0) ? pkbf(tt, yv) : 0u, 0u, 0u, 0u);

                f32x4 Cf[4], Ct[4];
#pragma unroll
                for (int t = 0; t < 4; ++t) {
                    Cf[t] = __builtin_amdgcn_mfma_f32_16x16x32_bf16(NF.Ain[t], Bty, NF.bIn[t], 0, 0, 0);
                    Ct[t] = __builtin_amdgcn_mfma_f32_16x16x32_bf16(NF.Ain[t], Btn, zc, 0, 0, 0);
                }
                s16x8 bf0, bf1, bt0, bt1;
                trans16t(Cf, Ct, bf0, bf1, bt0, bt1);
                hidden_tan(NF, 0, zc, bf0, bf1, bt0, bt1, Cf, Ct);
                trans16t(Cf, Ct, Bf0, Bf1, Bt0, Bt1);   // -> pipeline state
            }
        }
    }

    // ---------------- epilogue: residuals + reduction (all waves) ----------
    // All Y/dY stores happened before barrier 53 (executed by every wave).
    float acc = 0.0f;
    for (int it = tid; it < 816; it += 192) {
        if (it < 800) {
            const int n  = it >> 4;
            const int pp = it & 15;
            const float q    = qb[it];
            const float dYc  = dYb[it];
            const float Yn   = Yb[it];
            const float Yn1  = Yb[it + 16];
            const float dws  = dW[n * NPATH + (int)blockIdx.x * 16 + pp] * SQRT_DT;
            const float Ytil = fmaf(-q * q, DT_F, Yn) + (SIGMA_F * dYc) * dws;
            const float r    = Yn1 - Ytil;
            acc = fmaf(r, r, acc);
        } else {
            const int pp = it - 800;
            const float y50  = yb[NSTEP * 16 + pp];
            const float Y50  = Yb[NSTEP * 16 + pp];
            const float dY50 = dYb[NSTEP * 16 + pp];
            const float r1 = Y50 - y50 * y50;
            const float r2 = dY50 - 2.0f * y50;
            acc = fmaf(r1, r1, fmaf(r2, r2, acc));
        }
    }
#pragma unroll
    for (int off = 32; off > 0; off >>= 1) acc += __shfl_down(acc, off, 64);
    if (l == 0) partial[wv] = acc;
    __syncthreads();                                 // barrier 54
    if (tid == 0)
        atomicAdd(out, (partial[0] + partial[1] + partial[2]) * (1.0f / (float)NPATH));
}

// ================= host launch =================

extern "C" void kernel_launch(void* const* d_in, const int* in_sizes, int n_in,
                              void* d_out, int out_size, void* d_ws, size_t ws_size,
                              hipStream_t stream)
{
    const float* Y_Win  = (const float*)d_in[0];
    const float* Y_bin  = (const float*)d_in[1];
    const float* Y_Whid = (const float*)d_in[2];
    const float* Y_bhid = (const float*)d_in[3];
    const float* Y_Wout = (const float*)d_in[4];
    const float* Y_bout = (const float*)d_in[5];
    const float* q_Win  = (const float*)d_in[6];
    const float* q_bin  = (const float*)d_in[7];
    const float* q_Whid = (const float*)d_in[8];
    const float* q_bhid = (const float*)d_in[9];
    const float* q_Wout = (const float*)d_in[10];
    const float* q_bout = (const float*)d_in[11];
    const float* y0p    = (const float*)d_in[12];
    const float* dW     = (const float*)d_in[13];

    hipMemsetAsync(d_out, 0, sizeof(float), stream);

    fbsnn_fused<<<dim3(NPATH / 16), dim3(192), 0, stream>>>(
        Y_Win, Y_bin, Y_Whid, Y_bhid, Y_Wout, Y_bout,
        q_Win, q_bin, q_Whid, q_bhid, q_Wout, q_bout,
        y0p, dW, (float*)d_out);
}

// Round 15
// 144.564 us; speedup vs baseline: 1.0240x; 1.0240x over previous
//
#include <hip/hip_runtime.h>

// FBSNN loss — single fused kernel, bf16 MFMA 16x16x32, zero-shuffle layout.
//
// Round 15 = round 14 (4-step barrier intervals) with DE-RISKED fallbacks:
// the pack/sin/cos #else branches are plain C (manual RNE pack, __sinf) —
// r14's container failure may have been the raw-asm fallback failing to
// assemble. The builtin path (expected on this toolchain) is unchanged.
//
// 256 blocks x 192 threads (3 waves, 1 block/CU, paths 16*blk..16*blk+15):
//   wave 0  = producer: sequential q-net scan, stores y_n, q_n to LDS,
//             __syncthreads every 4 steps (13 barriers, not 53 — r13 showed
//             ~500 cyc/step of barrier+skew tax on a 2980-cyc step).
//   waves 1,2 = consumers: FULL Y-net+tangent steps; interval j processes
//             steps 4(j-1)..4(j-1)+3: wv1 takes +0,+2, wv2 takes +1,+3.
//             Consumer quota 2 x ~3000 cyc << producer 4 x ~2980 — slack.
//   epilogue: residuals from LDS + dW, one atomicAdd per block.
// Barrier audit: producer 12 in-loop (n&3==3, n<=47) + 1 post-loop = 13;
// consumers 13 interval barriers; then epilogue barrier + partial barrier.
// Interval j consumes steps <= 4j-1, all published by barrier j; step 50
// (terminal) consumed at j=13 after the post-loop barrier. No LDS races.
//
// Unit relabeling u = 8*qd + 4t + i (t<2; +32 for t>=2): each lane's 4 C/D
// tiles ARE its two next-layer B-frags in register order (zero cross-lane).
// Weights/biases prescaled by 1/2pi; tangent dh = cosrev(cf) * (2pi * Ct).

#define NPATH   4096
#define NSTEP   50
#define DT_F    0.02f
#define SQRT_DT 0.14142136f
#define SIGMA_F 0.5f
#define INV2PI  0.15915494309189535f
#define TWOPI_F 6.28318530717958648f

typedef __attribute__((ext_vector_type(8)))  short s16x8;
typedef __attribute__((ext_vector_type(4)))  float f32x4;

#if __has_builtin(__builtin_amdgcn_cvt_pk_bf16_f32)
__device__ __forceinline__ unsigned pkbf(float a, float b) {
    auto r = __builtin_amdgcn_cvt_pk_bf16_f32(a, b);   // RNE, 1 instr
    unsigned u; __builtin_memcpy(&u, &r, 4); return u;
}
#else
__device__ __forceinline__ unsigned pkbf(float a, float b) {
    unsigned ua = __float_as_uint(a), ub = __float_as_uint(b);
    ua += 0x7fffu + ((ua >> 16) & 1u);
    ub += 0x7fffu + ((ub >> 16) & 1u);
    return (ua >> 16) | (ub & 0xffff0000u);
}
#endif

__device__ __forceinline__ s16x8 frag4(unsigned a, unsigned b, unsigned c, unsigned d) {
    union { unsigned u[4]; s16x8 s; } x;
    x.u[0] = a; x.u[1] = b; x.u[2] = c; x.u[3] = d;
    return x.s;
}

__device__ __forceinline__ float sinrev(float x) {
#if __has_builtin(__builtin_amdgcn_sinf)
    return __builtin_amdgcn_sinf(x);      // input in revolutions
#else
    return __sinf(x * TWOPI_F);
#endif
}
__device__ __forceinline__ float cosrev(float x) {
#if __has_builtin(__builtin_amdgcn_cosf)
    return __builtin_amdgcn_cosf(x);
#else
    return __cosf(x * TWOPI_F);
#endif
}

// output unit produced at (tile t, C/D-row r)
__device__ __forceinline__ int slot16(int t, int r) {
    return (t < 2) ? 8 * (r >> 2) + 4 * t + (r & 3)
                   : 32 + 8 * (r >> 2) + 4 * (t - 2) + (r & 3);
}

struct NetFrags {
    s16x8 Ain[4];
    s16x8 AH[3][4][2];
    s16x8 Aout[2];
    f32x4 bIn[4];          // C-init vectors, consumed directly by MFMA
    f32x4 bHd[3][4];
    float bout;
};

__device__ __forceinline__ void build_net(
    const float* __restrict__ Win, const float* __restrict__ bin,
    const float* __restrict__ Whid, const float* __restrict__ bhid,
    const float* __restrict__ Wout, const float* __restrict__ bo,
    int qd, int m, NetFrags& NF)
{
#pragma unroll
    for (int t = 0; t < 4; ++t) {
        const int uo = slot16(t, m);
        unsigned w0 = 0;
        if (qd == 0) w0 = pkbf(INV2PI * Win[uo], INV2PI * Win[64 + uo]);
        NF.Ain[t] = frag4(w0, 0u, 0u, 0u);
#pragma unroll
        for (int L = 0; L < 3; ++L) {
            const float* W = Whid + L * 4096 + uo;
#pragma unroll
            for (int kk = 0; kk < 2; ++kk) {
                unsigned w[4];
#pragma unroll
                for (int j2 = 0; j2 < 4; ++j2) {
                    int e0 = 32 * kk + 8 * qd + 2 * j2;
                    w[j2] = pkbf(INV2PI * W[e0 * 64], INV2PI * W[(e0 + 1) * 64]);
                }
                NF.AH[L][t][kk] = frag4(w[0], w[1], w[2], w[3]);
            }
        }
#pragma unroll
        for (int i = 0; i < 4; ++i) {
            const int u = slot16(t, 4 * qd + i);
            NF.bIn[t][i] = INV2PI * bin[u];
#pragma unroll
            for (int L = 0; L < 3; ++L)
                NF.bHd[L][t][i] = INV2PI * bhid[L * 64 + u];
        }
    }
#pragma unroll
    for (int kk = 0; kk < 2; ++kk) {
        unsigned w[4] = {0u, 0u, 0u, 0u};
        if (m == 0) {
#pragma unroll
            for (int j2 = 0; j2 < 4; ++j2) {
                int e0 = 32 * kk + 8 * qd + 2 * j2;
                w[j2] = pkbf(Wout[e0], Wout[e0 + 1]);
            }
        }
        NF.Aout[kk] = frag4(w[0], w[1], w[2], w[3]);
    }
    NF.bout = bo[0];
}

// fwd transition: 4 C tiles -> 2 B-frags (sin + packed cvt)
__device__ __forceinline__ void trans16(const f32x4* C, s16x8& B0, s16x8& B1) {
    float a[4][4];
#pragma unroll
    for (int t = 0; t < 4; ++t)
#pragma unroll
        for (int i = 0; i < 4; ++i) a[t][i] = sinrev(C[t][i]);
    B0 = frag4(pkbf(a[0][0], a[0][1]), pkbf(a[0][2], a[0][3]),
               pkbf(a[1][0], a[1][1]), pkbf(a[1][2], a[1][3]));
    B1 = frag4(pkbf(a[2][0], a[2][1]), pkbf(a[2][2], a[2][3]),
               pkbf(a[3][0], a[3][1]), pkbf(a[3][2], a[3][3]));
}

// fwd+tangent transition
__device__ __forceinline__ void trans16t(const f32x4* Cf, const f32x4* Ct,
                                         s16x8& Bf0, s16x8& Bf1,
                                         s16x8& Bt0, s16x8& Bt1)
{
    float s[4][4], d[4][4];
#pragma unroll
    for (int t = 0; t < 4; ++t)
#pragma unroll
        for (int i = 0; i < 4; ++i) {
            float cf = Cf[t][i];
            s[t][i] = sinrev(cf);
            d[t][i] = cosrev(cf) * (TWOPI_F * Ct[t][i]);
        }
    Bf0 = frag4(pkbf(s[0][0], s[0][1]), pkbf(s[0][2], s[0][3]),
                pkbf(s[1][0], s[1][1]), pkbf(s[1][2], s[1][3]));
    Bf1 = frag4(pkbf(s[2][0], s[2][1]), pkbf(s[2][2], s[2][3]),
                pkbf(s[3][0], s[3][1]), pkbf(s[3][2], s[3][3]));
    Bt0 = frag4(pkbf(d[0][0], d[0][1]), pkbf(d[0][2], d[0][3]),
                pkbf(d[1][0], d[1][1]), pkbf(d[1][2], d[1][3]));
    Bt1 = frag4(pkbf(d[2][0], d[2][1]), pkbf(d[2][2], d[2][3]),
                pkbf(d[3][0], d[3][1]), pkbf(d[3][2], d[3][3]));
}

// one hidden layer with tangent: bias vec as C operand, zero vec for tangent
__device__ __forceinline__ void hidden_tan(const NetFrags& NF, int L,
    const f32x4& zc,
    const s16x8& Bf0, const s16x8& Bf1, const s16x8& Bt0, const s16x8& Bt1,
    f32x4* Cf, f32x4* Ct)
{
#pragma unroll
    for (int t = 0; t < 4; ++t) {
        f32x4 c = __builtin_amdgcn_mfma_f32_16x16x32_bf16(NF.AH[L][t][0], Bf0, NF.bHd[L][t], 0, 0, 0);
        Cf[t]   = __builtin_amdgcn_mfma_f32_16x16x32_bf16(NF.AH[L][t][1], Bf1, c, 0, 0, 0);
        f32x4 z = __builtin_amdgcn_mfma_f32_16x16x32_bf16(NF.AH[L][t][0], Bt0, zc, 0, 0, 0);
        Ct[t]   = __builtin_amdgcn_mfma_f32_16x16x32_bf16(NF.AH[L][t][1], Bt1, z, 0, 0, 0);
    }
}

// ================= fused kernel =================

extern "C" __global__ void __launch_bounds__(192, 1)
fbsnn_fused(const float* __restrict__ Y_Win, const float* __restrict__ Y_bin,
            const float* __restrict__ Y_Whid, const float* __restrict__ Y_bhid,
            const float* __restrict__ Y_Wout, const float* __restrict__ Y_bout,
            const float* __restrict__ q_Win, const float* __restrict__ q_bin,
            const float* __restrict__ q_Whid, const float* __restrict__ q_bhid,
            const float* __restrict__ q_Wout, const float* __restrict__ q_bout,
            const float* __restrict__ y0p, const float* __restrict__ dW,
            float* __restrict__ out)
{
    __shared__ float yb[51 * 16];      // y trajectory
    __shared__ float qb[50 * 16];      // control
    __shared__ float Yb[51 * 16];      // Y-net value
    __shared__ float dYb[51 * 16];     // Y-net tangent
    __shared__ float partial[3];

    const int tid = (int)threadIdx.x;
    const int wv  = tid >> 6;          // 0 = producer, 1/2 = consumers
    const int l   = tid & 63;
    const int qd  = l >> 4;
    const int m   = l & 15;
    const int p   = (int)blockIdx.x * 16 + m;

    const f32x4 zc = {0.0f, 0.0f, 0.0f, 0.0f};

    if (wv == 0) {
        // ---------------- producer: q-net scan ----------------
        NetFrags NF;
        build_net(q_Win, q_bin, q_Whid, q_bhid, q_Wout, q_bout, qd, m, NF);

        float y = y0p[0];
        float dw_cur = (qd == 0) ? dW[p] : 0.0f;

        for (int n = 0; n < NSTEP; ++n) {
            const float tt = n * DT_F;
            if (qd == 0) yb[n * 16 + m] = y;

            const int n1 = (n + 1 < NSTEP) ? n + 1 : NSTEP - 1;
            const float dw_next = (qd == 0) ? dW[n1 * NPATH + p] : 0.0f;

            const s16x8 Bty = frag4((qd == 0) ? pkbf(tt, y) : 0u, 0u, 0u, 0u);

            f32x4 C[4];
#pragma unroll
            for (int t = 0; t < 4; ++t)
                C[t] = __builtin_amdgcn_mfma_f32_16x16x32_bf16(NF.Ain[t], Bty, NF.bIn[t], 0, 0, 0);
            s16x8 B0, B1;
            trans16(C, B0, B1);

#pragma unroll
            for (int L = 0; L < 3; ++L) {
#pragma unroll
                for (int t = 0; t < 4; ++t) {
                    f32x4 c = __builtin_amdgcn_mfma_f32_16x16x32_bf16(NF.AH[L][t][0], B0, NF.bHd[L][t], 0, 0, 0);
                    C[t]    = __builtin_amdgcn_mfma_f32_16x16x32_bf16(NF.AH[L][t][1], B1, c, 0, 0, 0);
                }
                trans16(C, B0, B1);
            }

            f32x4 Co = __builtin_amdgcn_mfma_f32_16x16x32_bf16(NF.Aout[0], B0, zc, 0, 0, 0);
            Co = __builtin_amdgcn_mfma_f32_16x16x32_bf16(NF.Aout[1], B1, Co, 0, 0, 0);

            const float q = Co[0] + NF.bout;         // valid at qd==0, col=m
            if (qd == 0) qb[n * 16 + m] = q;
            y = fmaf(q, DT_F, y) + SIGMA_F * (dw_cur * SQRT_DT);
            dw_cur = dw_next;

            if ((n & 3) == 3 && n <= 47) __syncthreads();   // barriers 1..12
        }
        if (qd == 0) yb[NSTEP * 16 + m] = y;
        __syncthreads();                             // barrier 13
    } else {
        // -------- consumers: full Y-net+tangent steps, 4-step intervals ----
        NetFrags NF;
        build_net(Y_Win, Y_bin, Y_Whid, Y_bhid, Y_Wout, Y_bout, qd, m, NF);

        const int parity = wv - 1;
        const s16x8 Btn = frag4((qd == 0) ? pkbf(0.0f, 1.0f) : 0u, 0u, 0u, 0u);

        for (int j = 1; j <= 13; ++j) {
            __syncthreads();                         // barriers 1..13
            const int k0 = 4 * (j - 1) + parity;
#pragma unroll
            for (int d2 = 0; d2 < 2; ++d2) {
                const int k = k0 + 2 * d2;
                if (k > NSTEP) continue;             // only wv1 reaches k=50

                const float yv = yb[k * 16 + m];
                const float tt = k * DT_F;
                const s16x8 Bty = frag4((qd == 0) ? pkbf(tt, yv) : 0u, 0u, 0u, 0u);

                f32x4 Cf[4], Ct[4];
#pragma unroll
                for (int t = 0; t < 4; ++t) {
                    Cf[t] = __builtin_amdgcn_mfma_f32_16x16x32_bf16(NF.Ain[t], Bty, NF.bIn[t], 0, 0, 0);
                    Ct[t] = __builtin_amdgcn_mfma_f32_16x16x32_bf16(NF.Ain[t], Btn, zc, 0, 0, 0);
                }
                s16x8 bf0, bf1, bt0, bt1;
                trans16t(Cf, Ct, bf0, bf1, bt0, bt1);

#pragma unroll
                for (int L = 0; L < 3; ++L) {
                    hidden_tan(NF, L, zc, bf0, bf1, bt0, bt1, Cf, Ct);
                    trans16t(Cf, Ct, bf0, bf1, bt0, bt1);
                }

                f32x4 Cof = __builtin_amdgcn_mfma_f32_16x16x32_bf16(NF.Aout[0], bf0, zc, 0, 0, 0);
                Cof = __builtin_amdgcn_mfma_f32_16x16x32_bf16(NF.Aout[1], bf1, Cof, 0, 0, 0);
                f32x4 Cot = __builtin_amdgcn_mfma_f32_16x16x32_bf16(NF.Aout[0], bt0, zc, 0, 0, 0);
                Cot = __builtin_amdgcn_mfma_f32_16x16x32_bf16(NF.Aout[1], bt1, Cot, 0, 0, 0);

                if (qd == 0) {
                    Yb[k * 16 + m]  = Cof[0] + NF.bout;
                    dYb[k * 16 + m] = Cot[0];
                }
            }
        }
    }

    // ---------------- epilogue: residuals + reduction (all waves) ----------
    __syncthreads();                                 // barrier 14

    float acc = 0.0f;
    for (int it = tid; it < 816; it += 192) {
        if (it < 800) {
            const int n  = it >> 4;
            const int pp = it & 15;
            const float q    = qb[it];
            const float dYc  = dYb[it];
            const float Yn   = Yb[it];
            const float Yn1  = Yb[it + 16];
            const float dws  = dW[n * NPATH + (int)blockIdx.x * 16 + pp] * SQRT_DT;
            const float Ytil = fmaf(-q * q, DT_F, Yn) + (SIGMA_F * dYc) * dws;
            const float r    = Yn1 - Ytil;
            acc = fmaf(r, r, acc);
        } else {
            const int pp = it - 800;
            const float y50  = yb[NSTEP * 16 + pp];
            const float Y50  = Yb[NSTEP * 16 + pp];
            const float dY50 = dYb[NSTEP * 16 + pp];
            const float r1 = Y50 - y50 * y50;
            const float r2 = dY50 - 2.0f * y50;
            acc = fmaf(r1, r1, fmaf(r2, r2, acc));
        }
    }
#pragma unroll
    for (int off = 32; off > 0; off >>= 1) acc += __shfl_down(acc, off, 64);
    if (l == 0) partial[wv] = acc;
    __syncthreads();                                 // barrier 15
    if (tid == 0)
        atomicAdd(out, (partial[0] + partial[1] + partial[2]) * (1.0f / (float)NPATH));
}

// ================= host launch =================

extern "C" void kernel_launch(void* const* d_in, const int* in_sizes, int n_in,
                              void* d_out, int out_size, void* d_ws, size_t ws_size,
                              hipStream_t stream)
{
    const float* Y_Win  = (const float*)d_in[0];
    const float* Y_bin  = (const float*)d_in[1];
    const float* Y_Whid = (const float*)d_in[2];
    const float* Y_bhid = (const float*)d_in[3];
    const float* Y_Wout = (const float*)d_in[4];
    const float* Y_bout = (const float*)d_in[5];
    const float* q_Win  = (const float*)d_in[6];
    const float* q_bin  = (const float*)d_in[7];
    const float* q_Whid = (const float*)d_in[8];
    const float* q_bhid = (const float*)d_in[9];
    const float* q_Wout = (const float*)d_in[10];
    const float* q_bout = (const float*)d_in[11];
    const float* y0p    = (const float*)d_in[12];
    const float* dW     = (const float*)d_in[13];

    hipMemsetAsync(d_out, 0, sizeof(float), stream);

    fbsnn_fused<<<dim3(NPATH / 16), dim3(192), 0, stream>>>(
        Y_Win, Y_bin, Y_Whid, Y_bhid, Y_Wout, Y_bout,
        q_Win, q_bin, q_Whid, q_bhid, q_Wout, q_bout,
        y0p, dW, (float*)d_out);
}